// Round 1
// baseline (386.666 us; speedup 1.0000x reference)
//
#include <hip/hip_runtime.h>

// ---------------------------------------------------------------------------
// Problem constants (fixed by the reference):
//   N=400000 nodes, E=2000000 edges, B=8, C_IN=4, N_EDGE_TYPE=5,
//   N_NODE_TYPE=7, C_OUT=32, TEMB_CH=512, AVG_DEGREE=5, fan=55
// ---------------------------------------------------------------------------

// ---- time embedding, stage 1: sinusoidal + lin1 + swish -> h1[8,512] ------
__global__ __launch_bounds__(64) void temb1_kernel(
    const float* __restrict__ t, const float* __restrict__ W1,
    const float* __restrict__ b1, float* __restrict__ h1)
{
    __shared__ float emb[8][128];
    int tid = threadIdx.x;
    const float kStep = 9.210340371976184f / 63.0f;  // ln(10000)/(half-1)
    for (int i = tid; i < 8 * 64; i += 64) {
        int b = i >> 6, f = i & 63;
        float ang = t[b] * expf(-(float)f * kStep);
        emb[b][f] = sinf(ang);
        emb[b][64 + f] = cosf(ang);
    }
    __syncthreads();
    int j = blockIdx.x * 64 + tid;   // 8 blocks x 64 = 512 channels
    float acc[8];
    float bj = b1[j];
#pragma unroll
    for (int b = 0; b < 8; ++b) acc[b] = bj;
    for (int k = 0; k < 128; ++k) {
        float w = W1[k * 512 + j];
#pragma unroll
        for (int b = 0; b < 8; ++b) acc[b] += emb[b][k] * w;
    }
#pragma unroll
    for (int b = 0; b < 8; ++b) {
        float v = acc[b];
        h1[b * 512 + j] = v / (1.0f + expf(-v));   // swish
    }
}

// ---- time embedding, stage 2: lin2 + swish -> sw[8,512] -------------------
__global__ __launch_bounds__(64) void temb2_kernel(
    const float* __restrict__ h1, const float* __restrict__ W2,
    const float* __restrict__ b2, float* __restrict__ sw)
{
    __shared__ float h1s[4096];
    int tid = threadIdx.x;
    for (int i = tid; i < 4096; i += 64) h1s[i] = h1[i];
    __syncthreads();
    int j = blockIdx.x * 64 + tid;   // 8 blocks x 64 = 512 channels
    float acc[8];
    float bj = b2[j];
#pragma unroll
    for (int b = 0; b < 8; ++b) acc[b] = bj;
    for (int k = 0; k < 512; ++k) {
        float w = W2[k * 512 + j];
#pragma unroll
        for (int b = 0; b < 8; ++b) acc[b] += h1s[b * 512 + k] * w;
    }
#pragma unroll
    for (int b = 0; b < 8; ++b) {
        float v = acc[b];
        sw[b * 512 + j] = v / (1.0f + expf(-v));   // swish(temb)
    }
}

// ---- time embedding, stage 3: swish(temb) @ W_temb -> inj[8,32] -----------
__global__ __launch_bounds__(256) void temb3_kernel(
    const float* __restrict__ sw, const float* __restrict__ Wt,
    float* __restrict__ inj)
{
    __shared__ float sws[4096];
    int tid = threadIdx.x;
    for (int i = tid; i < 4096; i += 256) sws[i] = sw[i];
    __syncthreads();
    int b = tid >> 5, c = tid & 31;  // 256 threads = 8*32 outputs
    float acc = 0.f;
    for (int k = 0; k < 512; ++k) acc += sws[b * 512 + k] * Wt[k * 32 + c];
    inj[tid] = acc;
}

// ---- init: out[n,:] = inj[batch_id[n], :]  (float4 coalesced) -------------
__global__ __launch_bounds__(256) void init_kernel(
    const int* __restrict__ batch_id, const float* __restrict__ inj,
    float4* __restrict__ out, int N)
{
    int gid = blockIdx.x * 256 + threadIdx.x;
    if (gid >= N * 8) return;        // 8 float4 per node (32 ch)
    int n = gid >> 3, q = gid & 7;
    int b = batch_id[n];
    out[gid] = ((const float4*)inj)[b * 8 + q];
}

// ---- edges: out[row, c] += 0.2 * (x[col]·Wblk[0:4, c] + Wblk[4+nt, c]) ----
// thread = (edge, channel); W_conv (55x32 = 7KB) staged in LDS.
__global__ __launch_bounds__(256) void edge_kernel(
    const int* __restrict__ ei, const int* __restrict__ etype,
    const int* __restrict__ ntype, const float* __restrict__ x,
    const float* __restrict__ Wc, float* __restrict__ out, int E)
{
    __shared__ float Ws[55 * 32];
    for (int i = threadIdx.x; i < 55 * 32; i += 256) Ws[i] = Wc[i];
    __syncthreads();
    unsigned total = (unsigned)E * 32u;
    unsigned stride = gridDim.x * 256u;   // multiple of 32 -> c constant
    for (unsigned idx = blockIdx.x * 256u + threadIdx.x; idx < total;
         idx += stride) {
        int e = (int)(idx >> 5);
        int c = (int)(idx & 31);
        int row = ei[e];
        int col = ei[E + e];
        int T = etype[e];
        int nt = ntype[col];
        float4 xv = ((const float4*)x)[col];
        const float* wb = Ws + T * 352;   // T * 11 * 32
        float y = xv.x * wb[c] + xv.y * wb[32 + c] + xv.z * wb[64 + c] +
                  xv.w * wb[96 + c] + wb[(4 + nt) * 32 + c];
        atomicAdd(out + (size_t)row * 32 + c, y * 0.2f);
    }
}

extern "C" void kernel_launch(void* const* d_in, const int* in_sizes, int n_in,
                              void* d_out, int out_size, void* d_ws, size_t ws_size,
                              hipStream_t stream) {
    const float* x     = (const float*)d_in[0];   // [N,4]
    const float* t     = (const float*)d_in[1];   // [8]
    const int*   ei    = (const int*)d_in[2];     // [2,E]
    const int*   etype = (const int*)d_in[3];     // [E]
    const int*   ntype = (const int*)d_in[4];     // [N]
    const int*   batch = (const int*)d_in[5];     // [N]
    const float* Wc    = (const float*)d_in[6];   // [55,32]
    const float* W1    = (const float*)d_in[7];   // [128,512]
    const float* b1    = (const float*)d_in[8];   // [512]
    const float* W2    = (const float*)d_in[9];   // [512,512]
    const float* b2    = (const float*)d_in[10];  // [512]
    const float* Wt    = (const float*)d_in[11];  // [512,32]
    float* out = (float*)d_out;

    int E = in_sizes[3];
    int N = in_sizes[4];

    float* ws  = (float*)d_ws;
    float* h1  = ws;          // 4096 floats
    float* swb = ws + 4096;   // 4096 floats
    float* inj = ws + 8192;   // 256 floats

    temb1_kernel<<<8, 64, 0, stream>>>(t, W1, b1, h1);
    temb2_kernel<<<8, 64, 0, stream>>>(h1, W2, b2, swb);
    temb3_kernel<<<1, 256, 0, stream>>>(swb, Wt, inj);
    init_kernel<<<(N * 8 + 255) / 256, 256, 0, stream>>>(batch, inj,
                                                         (float4*)out, N);
    edge_kernel<<<16384, 256, 0, stream>>>(ei, etype, ntype, x, Wc, out, E);
}

// Round 2
// 367.219 us; speedup vs baseline: 1.0530x; 1.0530x over previous
//
#include <hip/hip_runtime.h>

// ---------------------------------------------------------------------------
// N=400000, E=2000000, B=8, C_IN=4, N_EDGE_TYPE=5, N_NODE_TYPE=7, C_OUT=32,
// TEMB_CH=512, AVG_DEGREE=5.
//
// Strategy: CSR build (count -> scan -> scatter, int atomics only), then a
// gather kernel: 8 threads/node, 4 channels each, one coalesced float4 store
// per thread (fuses inj[batch_id] init). Zero float atomics on the output.
// ---------------------------------------------------------------------------

// ---- temb stage 1 partials: emb @ W1 -> h1acc (pre-bias/swish) ------------
__global__ __launch_bounds__(64) void temb1_kernel(
    const float* __restrict__ t, const float* __restrict__ W1,
    float* __restrict__ h1acc)
{
    int jb = blockIdx.x & 7, ks = blockIdx.x >> 3;   // 8 j-tiles x 4 k-slices
    __shared__ float embs[8][32];
    int tid = threadIdx.x;
    const float kStep = 9.210340371976184f / 63.0f;  // ln(10000)/(half-1)
    for (int i = tid; i < 256; i += 64) {
        int b = i >> 5, kk = i & 31;
        int k = ks * 32 + kk;
        float v;
        if (k < 64) v = sinf(t[b] * expf(-(float)k * kStep));
        else        v = cosf(t[b] * expf(-(float)(k - 64) * kStep));
        embs[b][kk] = v;
    }
    __syncthreads();
    int j = jb * 64 + tid;
    float acc[8] = {};
    for (int kk = 0; kk < 32; ++kk) {
        float w = W1[(ks * 32 + kk) * 512 + j];
#pragma unroll
        for (int b = 0; b < 8; ++b) acc[b] += embs[b][kk] * w;
    }
#pragma unroll
    for (int b = 0; b < 8; ++b) atomicAdd(&h1acc[b * 512 + j], acc[b]);
}

// ---- temb stage 2 partials: swish(h1+b1) @ W2 -> h2acc --------------------
__global__ __launch_bounds__(64) void temb2_kernel(
    const float* __restrict__ h1acc, const float* __restrict__ b1,
    const float* __restrict__ W2, float* __restrict__ h2acc)
{
    int jb = blockIdx.x & 7, ks = blockIdx.x >> 3;   // 8 j-tiles x 8 k-slices
    __shared__ float h1s[8][64];
    int tid = threadIdx.x;
    for (int i = tid; i < 512; i += 64) {
        int b = i >> 6, kk = i & 63;
        int k = ks * 64 + kk;
        float v = h1acc[b * 512 + k] + b1[k];
        h1s[b][kk] = v / (1.0f + expf(-v));          // swish
    }
    __syncthreads();
    int j = jb * 64 + tid;
    float acc[8] = {};
    for (int kk = 0; kk < 64; ++kk) {
        float w = W2[(ks * 64 + kk) * 512 + j];
#pragma unroll
        for (int b = 0; b < 8; ++b) acc[b] += h1s[b][kk] * w;
    }
#pragma unroll
    for (int b = 0; b < 8; ++b) atomicAdd(&h2acc[b * 512 + j], acc[b]);
}

// ---- temb stage 3 partials: swish(h2+b2) @ W_temb -> inj[8,32] ------------
__global__ __launch_bounds__(256) void temb3_kernel(
    const float* __restrict__ h2acc, const float* __restrict__ b2,
    const float* __restrict__ Wt, float* __restrict__ inj)
{
    int ks = blockIdx.x;                              // 8 k-slices
    __shared__ float sws[8][64];
    int tid = threadIdx.x;
    for (int i = tid; i < 512; i += 256) {
        int b = i >> 6, kk = i & 63;
        int k = ks * 64 + kk;
        float v = h2acc[b * 512 + k] + b2[k];
        sws[b][kk] = v / (1.0f + expf(-v));           // swish(temb)
    }
    __syncthreads();
    int b = tid >> 5, c = tid & 31;
    float acc = 0.f;
    for (int kk = 0; kk < 64; ++kk)
        acc += sws[b][kk] * Wt[(ks * 64 + kk) * 32 + c];
    atomicAdd(&inj[tid], acc);
}

// ---- degree count ---------------------------------------------------------
__global__ __launch_bounds__(256) void count_kernel(
    const int* __restrict__ ei, int* __restrict__ deg, int E)
{
    int e = blockIdx.x * 256 + threadIdx.x;
    if (e < E) atomicAdd(&deg[ei[e]], 1);
}

// ---- scan A: per-block sums of deg (1024 elems/block) ---------------------
__global__ __launch_bounds__(256) void scanA_kernel(
    const int* __restrict__ deg, int* __restrict__ bsums, int N)
{
    __shared__ int s[256];
    int tid = threadIdx.x;
    int base = blockIdx.x * 1024 + tid * 4;
    int p = 0;
#pragma unroll
    for (int i = 0; i < 4; ++i) { int idx = base + i; if (idx < N) p += deg[idx]; }
    s[tid] = p; __syncthreads();
    for (int off = 128; off > 0; off >>= 1) {
        if (tid < off) s[tid] += s[tid + off];
        __syncthreads();
    }
    if (tid == 0) bsums[blockIdx.x] = s[0];
}

// ---- scan B: exclusive scan of block sums (single block) ------------------
__global__ __launch_bounds__(512) void scanB_kernel(int* __restrict__ bsums, int nb)
{
    __shared__ int s[512];
    int tid = threadIdx.x;
    int v = (tid < nb) ? bsums[tid] : 0;
    s[tid] = v; __syncthreads();
    for (int off = 1; off < 512; off <<= 1) {
        int u = (tid >= off) ? s[tid - off] : 0;
        __syncthreads();
        s[tid] += u;
        __syncthreads();
    }
    if (tid < nb) bsums[tid] = s[tid] - v;            // exclusive
}

// ---- scan C: final starts + cursor ----------------------------------------
__global__ __launch_bounds__(256) void scanC_kernel(
    const int* __restrict__ deg, const int* __restrict__ bsums,
    int* __restrict__ start, int* __restrict__ cursor, int N, int E)
{
    __shared__ int s[256];
    int tid = threadIdx.x;
    int base = blockIdx.x * 1024 + tid * 4;
    int d[4]; int p = 0;
#pragma unroll
    for (int i = 0; i < 4; ++i) {
        d[i] = (base + i < N) ? deg[base + i] : 0;
        p += d[i];
    }
    s[tid] = p; __syncthreads();
    for (int off = 1; off < 256; off <<= 1) {
        int u = (tid >= off) ? s[tid - off] : 0;
        __syncthreads();
        s[tid] += u;
        __syncthreads();
    }
    int run = bsums[blockIdx.x] + (s[tid] - p);       // exclusive within grid
#pragma unroll
    for (int i = 0; i < 4; ++i) {
        if (base + i < N) { start[base + i] = run; cursor[base + i] = run; run += d[i]; }
    }
    if (blockIdx.x == 0 && tid == 0) start[N] = E;
}

// ---- scatter: payload[slot] = col | T<<19 | nt<<22 ------------------------
__global__ __launch_bounds__(256) void scatter_kernel(
    const int* __restrict__ ei, const int* __restrict__ etype,
    const int* __restrict__ ntype, int* __restrict__ cursor,
    int* __restrict__ payload, int E)
{
    int e = blockIdx.x * 256 + threadIdx.x;
    if (e >= E) return;
    int row = ei[e], col = ei[E + e];
    int T = etype[e], nt = ntype[col];
    int slot = atomicAdd(&cursor[row], 1);
    payload[slot] = col | (T << 19) | (nt << 22);
}

// ---- gather: 8 threads/node, 4 channels each, one float4 store ------------
// Ws uses T-stride 356 (=11*32+4 pad) so different T map to different banks.
__global__ __launch_bounds__(256) void gather_kernel(
    const int* __restrict__ start, const int* __restrict__ payload,
    const float* __restrict__ x, const float* __restrict__ Wc,
    const int* __restrict__ batch, const float* __restrict__ inj,
    float* __restrict__ out, int N)
{
    __shared__ float Ws[5 * 356];
    for (int i = threadIdx.x; i < 55 * 32; i += 256) {
        int T = i / 352, rem = i - T * 352;
        Ws[T * 356 + rem] = Wc[i];
    }
    __syncthreads();
    int gid = blockIdx.x * 256 + threadIdx.x;
    if (gid >= N * 8) return;
    int n = gid >> 3, q = gid & 7;                    // channel quad
    int s = start[n], e = start[n + 1];
    float4 acc = {0.f, 0.f, 0.f, 0.f};
    for (int j = s; j < e; ++j) {
        int p = payload[j];
        int col = p & 0x7FFFF;
        int T = (p >> 19) & 7;
        int nt = p >> 22;
        float4 xv = ((const float4*)x)[col];
        const float4* wb = (const float4*)(Ws + T * 356) + q;
        float4 w0 = wb[0], w1 = wb[8], w2 = wb[16], w3 = wb[24];
        float4 w4 = wb[(4 + nt) * 8];
        acc.x += xv.x * w0.x + xv.y * w1.x + xv.z * w2.x + xv.w * w3.x + w4.x;
        acc.y += xv.x * w0.y + xv.y * w1.y + xv.z * w2.y + xv.w * w3.y + w4.y;
        acc.z += xv.x * w0.z + xv.y * w1.z + xv.z * w2.z + xv.w * w3.z + w4.z;
        acc.w += xv.x * w0.w + xv.y * w1.w + xv.z * w2.w + xv.w * w3.w + w4.w;
    }
    int b = batch[n];
    float4 iv = ((const float4*)inj)[b * 8 + q];
    float4 o;
    o.x = iv.x + 0.2f * acc.x;
    o.y = iv.y + 0.2f * acc.y;
    o.z = iv.z + 0.2f * acc.z;
    o.w = iv.w + 0.2f * acc.w;
    ((float4*)out)[gid] = o;
}

extern "C" void kernel_launch(void* const* d_in, const int* in_sizes, int n_in,
                              void* d_out, int out_size, void* d_ws, size_t ws_size,
                              hipStream_t stream) {
    const float* x     = (const float*)d_in[0];   // [N,4]
    const float* t     = (const float*)d_in[1];   // [8]
    const int*   ei    = (const int*)d_in[2];     // [2,E]
    const int*   etype = (const int*)d_in[3];     // [E]
    const int*   ntype = (const int*)d_in[4];     // [N]
    const int*   batch = (const int*)d_in[5];     // [N]
    const float* Wc    = (const float*)d_in[6];   // [55,32]
    const float* W1    = (const float*)d_in[7];   // [128,512]
    const float* b1    = (const float*)d_in[8];   // [512]
    const float* W2    = (const float*)d_in[9];   // [512,512]
    const float* b2    = (const float*)d_in[10];  // [512]
    const float* Wt    = (const float*)d_in[11];  // [512,32]
    float* out = (float*)d_out;

    int E = in_sizes[3];
    int N = in_sizes[4];
    int nb = (N + 1023) / 1024;                   // scan blocks (<=512)

    // ws layout (4-byte units)
    float* ws     = (float*)d_ws;
    float* h1acc  = ws;                           // 4096
    float* h2acc  = ws + 4096;                    // 4096
    float* inj    = ws + 8192;                    // 256
    int*   deg    = (int*)(ws + 8448);            // N   (zeroed)
    int*   cursor = deg + N;                      // N
    int*   start  = cursor + N;                   // N+1
    int*   bsums  = start + N + 1;                // 512
    int*   payload= bsums + 512;                  // E

    // zero h1acc/h2acc/inj/deg in one memset
    hipMemsetAsync(d_ws, 0, (size_t)(8448 + N) * 4, stream);

    temb1_kernel<<<32, 64, 0, stream>>>(t, W1, h1acc);
    temb2_kernel<<<64, 64, 0, stream>>>(h1acc, b1, W2, h2acc);
    temb3_kernel<<<8, 256, 0, stream>>>(h2acc, b2, Wt, inj);

    int egrid = (E + 255) / 256;
    count_kernel<<<egrid, 256, 0, stream>>>(ei, deg, E);
    scanA_kernel<<<nb, 256, 0, stream>>>(deg, bsums, N);
    scanB_kernel<<<1, 512, 0, stream>>>(bsums, nb);
    scanC_kernel<<<nb, 256, 0, stream>>>(deg, bsums, start, cursor, N, E);
    scatter_kernel<<<egrid, 256, 0, stream>>>(ei, etype, ntype, cursor, payload, E);

    gather_kernel<<<(N * 8 + 255) / 256, 256, 0, stream>>>(
        start, payload, x, Wc, batch, inj, out, N);
}